// Round 10
// baseline (416.025 us; speedup 1.0000x reference)
//
#include <hip/hip_runtime.h>
#include <hip/hip_fp16.h>
#include <math.h>

#define F_IN  256
#define F_HID 64
#define F_OUT 40
#define HS2_LD 64   // fp16 row stride: 64*2B = one 128B line

typedef _Float16 h8 __attribute__((ext_vector_type(8)));
typedef _Float16 h4 __attribute__((ext_vector_type(4)));
typedef float f4 __attribute__((ext_vector_type(4)));

// ---------------------------------------------------------------- degree histogram (int)
__global__ void k_deg(const int* __restrict__ dst, unsigned* __restrict__ degc, int E) {
    int i = blockIdx.x * blockDim.x + threadIdx.x;
    if (i < E) atomicAdd(&degc[dst[i]], 1u);
}

// ---------------------------------------------------------------- scan of PADDED degrees -> rowptr
__global__ __launch_bounds__(256) void k_scanA(const unsigned* __restrict__ degc,
                                               unsigned* __restrict__ exscan,
                                               unsigned* __restrict__ bsum, int N) {
    __shared__ unsigned s[256];
    int tid = threadIdx.x;
    int i = blockIdx.x * 256 + tid;
    unsigned v = (i < N) ? ((degc[i] + 8u) & ~7u) : 0u;
    s[tid] = v;
    __syncthreads();
    for (int off = 1; off < 256; off <<= 1) {
        unsigned t = (tid >= off) ? s[tid - off] : 0u;
        __syncthreads();
        s[tid] += t;
        __syncthreads();
    }
    if (i < N) exscan[i] = s[tid] - v;
    if (tid == 255) bsum[blockIdx.x] = s[255];
}

__global__ __launch_bounds__(512) void k_scanB(unsigned* __restrict__ bsum, int nb) {
    __shared__ unsigned s[512];
    int tid = threadIdx.x;
    unsigned v = (tid < nb) ? bsum[tid] : 0u;
    s[tid] = v;
    __syncthreads();
    for (int off = 1; off < 512; off <<= 1) {
        unsigned t = (tid >= off) ? s[tid - off] : 0u;
        __syncthreads();
        s[tid] += t;
        __syncthreads();
    }
    if (tid < nb) bsum[tid] = s[tid] - v;  // exclusive
}

__global__ void k_scanC(const unsigned* __restrict__ degc, const unsigned* __restrict__ exscan,
                        const unsigned* __restrict__ bsum, unsigned* __restrict__ rowptr,
                        float* __restrict__ dinv, int N) {
    int i = blockIdx.x * blockDim.x + threadIdx.x;
    if (i < N) {
        unsigned rp = exscan[i] + bsum[i >> 8];
        rowptr[i] = rp;
        dinv[i] = rsqrtf((float)degc[i] + 1.0f);  // +1 self loop
        if (i == N - 1) rowptr[N] = rp + ((degc[i] + 8u) & ~7u);
        if (i == 0) dinv[N] = 1.0f;               // sentinel
    }
}

// ---------------------------------------------------------------- fill + pad (merged; disjoint slots)
__global__ void k_fillpad(const int* __restrict__ src, const int* __restrict__ dst,
                          const unsigned* __restrict__ degc,
                          const unsigned* __restrict__ rowptr, unsigned* __restrict__ cursor,
                          unsigned* __restrict__ colp, int E, int N) {
    int t = blockIdx.x * blockDim.x + threadIdx.x;
    if (t < E) {
        int d = dst[t];
        unsigned p = atomicAdd(&cursor[d], 1u);
        colp[rowptr[d] + p] = (unsigned)src[t];
    } else if (t < E + N) {
        int i = t - E;
        unsigned d = degc[i];
        unsigned base = rowptr[i];
        unsigned pd = (d + 8u) & ~7u;
        colp[base + d] = (unsigned)i;  // self loop
        for (unsigned p = d + 1; p < pd; ++p) colp[base + p] = (unsigned)N;
    }
}

// ---------------------------------------------------------------- weight prep (merged)
__global__ void k_wprep(const float* __restrict__ W1, const float* __restrict__ W2,
                        __half* __restrict__ Wt, __half* __restrict__ W2t) {
    int i = blockIdx.x * 256 + threadIdx.x;  // 16384 + 4096 = 20480
    if (i < 16384) {
        int k = i >> 6, n = i & 63;
        Wt[n * 256 + k] = __float2half(W1[i]);
    } else if (i < 20480) {
        int j = i - 16384;
        int n = j >> 6, k = j & 63;
        W2t[n * 64 + k] = __float2half((n < F_OUT) ? W2[k * F_OUT + n] : 0.f);
    }
}

// ---------------------------------------------------------------- hs1 = (x @ W1) * dinv, fp16, MFMA
#define XS 136
__global__ __launch_bounds__(256) void k_mm1(const float* __restrict__ x,
                                             const __half* __restrict__ Wth,
                                             const float* __restrict__ dinv,
                                             __half* __restrict__ hs1o, int N) {
    __shared__ _Float16 sX[64 * XS];  // 17408 B
    const _Float16* Wt = (const _Float16*)Wth;
    _Float16* hs1 = (_Float16*)hs1o;
    int tid = threadIdx.x;
    int lane = tid & 63;
    int wv = tid >> 6;
    int m15 = lane & 15;
    int q = lane >> 4;
    int nbase = blockIdx.x * 64;

    h8 bf[8];
    #pragma unroll
    for (int kt = 0; kt < 8; ++kt)
        bf[kt] = *(const h8*)(Wt + (wv * 16 + m15) * 256 + kt * 32 + q * 8);

    f4 acc[4];
    #pragma unroll
    for (int mt = 0; mt < 4; ++mt) acc[mt] = (f4){0.f, 0.f, 0.f, 0.f};

    #pragma unroll
    for (int c = 0; c < 2; ++c) {
        #pragma unroll
        for (int p = 0; p < 8; ++p) {
            int idx = p * 256 + tid;
            int row = idx >> 5;
            int c4  = idx & 31;
            int node = nbase + row;
            float4 v = (node < N) ? *(const float4*)(x + (size_t)node * F_IN + c * 128 + c4 * 4)
                                  : make_float4(0.f, 0.f, 0.f, 0.f);
            h4 hv = { (_Float16)v.x, (_Float16)v.y, (_Float16)v.z, (_Float16)v.w };
            *(h4*)&sX[row * XS + c4 * 4] = hv;
        }
        __syncthreads();
        #pragma unroll
        for (int kt2 = 0; kt2 < 4; ++kt2) {
            #pragma unroll
            for (int mt = 0; mt < 4; ++mt) {
                h8 a = *(const h8*)&sX[(mt * 16 + m15) * XS + kt2 * 32 + q * 8];
                acc[mt] = __builtin_amdgcn_mfma_f32_16x16x32_f16(a, bf[c * 4 + kt2], acc[mt], 0, 0, 0);
            }
        }
        __syncthreads();
    }

    #pragma unroll
    for (int mt = 0; mt < 4; ++mt) {
        #pragma unroll
        for (int r = 0; r < 4; ++r) {
            int node = nbase + mt * 16 + q * 4 + r;
            if (node <= N) {
                float din = (node < N) ? dinv[node] : 1.0f;
                hs1[(size_t)node * F_HID + wv * 16 + m15] = (_Float16)(acc[mt][r] * din);
            }
        }
    }
}

// ---------------------------------------------------------------- FUSED gather-1 + mm2
// Block = 64-node tile. Phase 1: each wave gathers 16 nodes (2-at-a-time A/B interleave),
// writes relu(acc*din + b1) rows as fp16 into LDS. Phase 2: mm2 MFMA from LDS, W2t frags
// in VGPRs, writes hs2 = (agg1 @ W2) * dinv directly.
#define AS 72   // 144 B LDS row stride: 16B-aligned, bank-stride 4 (2-way, free)
__global__ __launch_bounds__(256) void k_aggmm2(const unsigned* __restrict__ rowptr,
                                                const unsigned* __restrict__ colp,
                                                const float* __restrict__ dinv,
                                                const __half* __restrict__ hs1o,
                                                const float* __restrict__ bias1,
                                                const __half* __restrict__ W2th,
                                                __half* __restrict__ hs2o, int N) {
    __shared__ _Float16 sA[64 * AS];  // 9216 B
    const _Float16* hp = (const _Float16*)hs1o;
    const _Float16* W2t = (const _Float16*)W2th;
    _Float16* hs2 = (_Float16*)hs2o;
    int tid = threadIdx.x;
    int lane = tid & 63;
    int wv = tid >> 6;
    int m15 = lane & 15;
    int q = lane >> 4;
    int g = lane >> 3, c = lane & 7;
    int nbase = blockIdx.x * 64;

    // B-frags for phase 2 (issued early, independent of phase 1)
    h8 bfW[2];
    #pragma unroll
    for (int kt = 0; kt < 2; ++kt)
        bfW[kt] = *(const h8*)(W2t + (wv * 16 + m15) * 64 + kt * 32 + q * 8);

    // bias chunk for this lane's c
    float bv[8];
    *(float4*)&bv[0] = *(const float4*)(bias1 + c * 8);
    *(float4*)&bv[4] = *(const float4*)(bias1 + c * 8 + 4);

    // ---- phase 1: gather 16 nodes per wave, pairs (A,B)
    for (int p2 = 0; p2 < 8; ++p2) {
        int rowA = wv * 16 + 2 * p2;
        int na = nbase + rowA, nb = na + 1;
        bool doA = (na < N), doB = (nb < N);

        float accA[8], accB[8];
        #pragma unroll
        for (int j = 0; j < 8; ++j) { accA[j] = 0.f; accB[j] = 0.f; }

        unsigned aE = 0, aEnd = 0, bE = 0, bEnd = 0;
        if (doA) { aE = rowptr[na]; aEnd = rowptr[na + 1]; }
        if (doB) { bE = rowptr[nb]; bEnd = rowptr[nb + 1]; }

        while (aE < aEnd && bE < bEnd) {
            unsigned sAi = colp[aE + g];
            unsigned sBi = colp[bE + g];
            h8 va = *(const h8*)(hp + (size_t)sAi * F_HID + c * 8);
            h8 vb = *(const h8*)(hp + (size_t)sBi * F_HID + c * 8);
            #pragma unroll
            for (int j = 0; j < 8; ++j) { accA[j] += (float)va[j]; accB[j] += (float)vb[j]; }
            aE += 8; bE += 8;
        }
        while (aE < aEnd) {
            unsigned sAi = colp[aE + g];
            h8 va = *(const h8*)(hp + (size_t)sAi * F_HID + c * 8);
            #pragma unroll
            for (int j = 0; j < 8; ++j) accA[j] += (float)va[j];
            aE += 8;
        }
        while (bE < bEnd) {
            unsigned sBi = colp[bE + g];
            h8 vb = *(const h8*)(hp + (size_t)sBi * F_HID + c * 8);
            #pragma unroll
            for (int j = 0; j < 8; ++j) accB[j] += (float)vb[j];
            bE += 8;
        }

        #pragma unroll
        for (int off = 8; off <= 32; off <<= 1) {
            #pragma unroll
            for (int j = 0; j < 8; ++j) {
                accA[j] += __shfl_xor(accA[j], off, 64);
                accB[j] += __shfl_xor(accB[j], off, 64);
            }
        }

        if (g == 0) {  // lanes 0..7: chunk c
            h8 ho;
            float dinA = doA ? dinv[na] : 0.f;
            #pragma unroll
            for (int j = 0; j < 8; ++j)
                ho[j] = doA ? (_Float16)fmaxf(accA[j] * dinA + bv[j], 0.f) : (_Float16)0.f;
            *(h8*)&sA[rowA * AS + c * 8] = ho;
            float dinB = doB ? dinv[nb] : 0.f;
            #pragma unroll
            for (int j = 0; j < 8; ++j)
                ho[j] = doB ? (_Float16)fmaxf(accB[j] * dinB + bv[j], 0.f) : (_Float16)0.f;
            *(h8*)&sA[(rowA + 1) * AS + c * 8] = ho;
        }
    }
    __syncthreads();

    // ---- phase 2: mm2 MFMA
    f4 acc[4];
    #pragma unroll
    for (int mt = 0; mt < 4; ++mt) acc[mt] = (f4){0.f, 0.f, 0.f, 0.f};
    #pragma unroll
    for (int kt = 0; kt < 2; ++kt) {
        #pragma unroll
        for (int mt = 0; mt < 4; ++mt) {
            h8 a = *(const h8*)&sA[(mt * 16 + m15) * AS + kt * 32 + q * 8];
            acc[mt] = __builtin_amdgcn_mfma_f32_16x16x32_f16(a, bfW[kt], acc[mt], 0, 0, 0);
        }
    }

    #pragma unroll
    for (int mt = 0; mt < 4; ++mt) {
        #pragma unroll
        for (int r = 0; r < 4; ++r) {
            int node = nbase + mt * 16 + q * 4 + r;
            if (node <= N) {
                float din = (node < N) ? dinv[node] : 1.0f;
                hs2[(size_t)node * HS2_LD + wv * 16 + m15] = (_Float16)(acc[mt][r] * din);
            }
        }
    }
}

// ---------------------------------------------------------------- gather layer 2 (fp16, vectorized)
__global__ __launch_bounds__(256) void k_agg2(const unsigned* __restrict__ rowptr,
                                              const unsigned* __restrict__ colp,
                                              const float* __restrict__ dinv,
                                              const __half* __restrict__ hs2o,
                                              float* __restrict__ out,
                                              float* __restrict__ colsum, int N) {
    __shared__ float part[4][8][8];
    const _Float16* hp = (const _Float16*)hs2o;
    int lane = threadIdx.x & 63;
    int wv = threadIdx.x >> 6;
    int g = lane >> 3, c = lane & 7;
    int nwaves = gridDim.x * 4;
    float csum[8];
    #pragma unroll
    for (int j = 0; j < 8; ++j) csum[j] = 0.f;

    for (int w = blockIdx.x * 4 + wv; 2 * w < N; w += nwaves) {
        int na = 2 * w, nb = 2 * w + 1;
        float accA[8], accB[8];
        #pragma unroll
        for (int j = 0; j < 8; ++j) { accA[j] = 0.f; accB[j] = 0.f; }

        unsigned aE = rowptr[na], aEnd = rowptr[na + 1];
        bool hasB = (nb < N);
        unsigned bE = 0, bEnd = 0;
        if (hasB) { bE = rowptr[nb]; bEnd = rowptr[nb + 1]; }

        while (aE < aEnd && bE < bEnd) {
            unsigned sA = colp[aE + g];
            unsigned sB = colp[bE + g];
            h8 va = *(const h8*)(hp + (size_t)sA * HS2_LD + c * 8);
            h8 vb = *(const h8*)(hp + (size_t)sB * HS2_LD + c * 8);
            #pragma unroll
            for (int j = 0; j < 8; ++j) { accA[j] += (float)va[j]; accB[j] += (float)vb[j]; }
            aE += 8; bE += 8;
        }
        while (aE < aEnd) {
            unsigned sA = colp[aE + g];
            h8 va = *(const h8*)(hp + (size_t)sA * HS2_LD + c * 8);
            #pragma unroll
            for (int j = 0; j < 8; ++j) accA[j] += (float)va[j];
            aE += 8;
        }
        while (bE < bEnd) {
            unsigned sB = colp[bE + g];
            h8 vb = *(const h8*)(hp + (size_t)sB * HS2_LD + c * 8);
            #pragma unroll
            for (int j = 0; j < 8; ++j) accB[j] += (float)vb[j];
            bE += 8;
        }

        #pragma unroll
        for (int off = 8; off <= 32; off <<= 1) {
            #pragma unroll
            for (int j = 0; j < 8; ++j) {
                accA[j] += __shfl_xor(accA[j], off, 64);
                accB[j] += __shfl_xor(accB[j], off, 64);
            }
        }

        if (g == 0) {
            float dinA = dinv[na];
            #pragma unroll
            for (int j = 0; j < 8; ++j) { accA[j] *= dinA; csum[j] += accA[j]; }
            if (c < 5) {
                *(float4*)(out + (size_t)na * F_OUT + c * 8) =
                    make_float4(accA[0], accA[1], accA[2], accA[3]);
                *(float4*)(out + (size_t)na * F_OUT + c * 8 + 4) =
                    make_float4(accA[4], accA[5], accA[6], accA[7]);
            }
            if (hasB) {
                float dinB = dinv[nb];
                #pragma unroll
                for (int j = 0; j < 8; ++j) { accB[j] *= dinB; csum[j] += accB[j]; }
                if (c < 5) {
                    *(float4*)(out + (size_t)nb * F_OUT + c * 8) =
                        make_float4(accB[0], accB[1], accB[2], accB[3]);
                    *(float4*)(out + (size_t)nb * F_OUT + c * 8 + 4) =
                        make_float4(accB[4], accB[5], accB[6], accB[7]);
                }
            }
        }
    }

    if (g == 0) {
        #pragma unroll
        for (int j = 0; j < 8; ++j) part[wv][c][j] = csum[j];
    }
    __syncthreads();
    int tid = threadIdx.x;
    if (tid < F_OUT) {
        int cc = tid >> 3, jj = tid & 7;
        float s = part[0][cc][jj] + part[1][cc][jj] + part[2][cc][jj] + part[3][cc][jj];
        atomicAdd(&colsum[tid], s);
    }
}

// ---------------------------------------------------------------- PairNorm-SI + log_softmax
__global__ __launch_bounds__(128) void k_final(float* __restrict__ out,
                                               const float* __restrict__ colsum, int N) {
    __shared__ float sMean[F_OUT];
    if (threadIdx.x < F_OUT) sMean[threadIdx.x] = colsum[threadIdx.x] * (1.0f / (float)N);
    __syncthreads();
    int n = blockIdx.x * blockDim.x + threadIdx.x;
    if (n >= N) return;
    float* row = out + (size_t)n * F_OUT;
    float v[F_OUT];
    float ss = 0.f;
    #pragma unroll
    for (int f = 0; f < F_OUT; ++f) {
        float t = row[f] - sMean[f];
        v[f] = t;
        ss += t * t;
    }
    float scale = 1.0f / sqrtf(ss + 1e-6f);
    float m = -1e30f;
    #pragma unroll
    for (int f = 0; f < F_OUT; ++f) {
        float y = v[f] * scale;
        v[f] = y;
        m = fmaxf(m, y);
    }
    float sum = 0.f;
    #pragma unroll
    for (int f = 0; f < F_OUT; ++f) sum += expf(v[f] - m);
    float lse = logf(sum);
    #pragma unroll
    for (int f = 0; f < F_OUT; ++f) row[f] = v[f] - m - lse;
}

extern "C" void kernel_launch(void* const* d_in, const int* in_sizes, int n_in,
                              void* d_out, int out_size, void* d_ws, size_t ws_size,
                              hipStream_t stream) {
    const float* x  = (const float*)d_in[0];
    const int*   ei = (const int*)d_in[1];   // int32 per harness (verified R1)
    const float* W1 = (const float*)d_in[2];
    const float* b1 = (const float*)d_in[3];
    const float* W2 = (const float*)d_in[4];
    // b2 unused: cancels under PairNorm mean subtraction.
    float* out = (float*)d_out;

    int N = in_sizes[0] / F_IN;
    int E = in_sizes[1] / 2;
    const int* src = ei;
    const int* dst = ei + E;

    // byte layout with 128B alignment per region
    char* p = (char*)d_ws;
    auto alloc = [&](size_t bytes) { char* r = p; p += (bytes + 127) & ~(size_t)127; return r; };
    unsigned* degc   = (unsigned*)alloc((size_t)N * 4);
    unsigned* cursor = (unsigned*)alloc((size_t)N * 4);
    float*    colsum = (float*)   alloc(64 * 4);
    unsigned* rowptr = (unsigned*)alloc((size_t)(N + 1) * 4);
    unsigned* colp   = (unsigned*)alloc((size_t)(E + 8 * N + 8) * 4);
    float*    dinv   = (float*)   alloc((size_t)(N + 1) * 4);
    __half*   hs1    = (__half*)  alloc((size_t)64 * (N + 1) * 2);
    __half*   hs2    = (__half*)  alloc((size_t)64 * (N + 1) * 2);
    __half*   Wt     = (__half*)  alloc((size_t)16384 * 2);
    __half*   W2t    = (__half*)  alloc((size_t)4096 * 2);
    unsigned* exscan = (unsigned*)hs2;       // alias, CSR build only (hs2 written later)
    unsigned* bsum   = exscan + N;

    // zero degc + cursor (contiguous regions at ws start) + colsum
    hipMemsetAsync(d_ws, 0, (char*)(colsum + 64) - (char*)d_ws, stream);

    int nA = (N + 255) / 256;  // 391 for N=100000, <= 512 for k_scanB
    k_deg<<<(E + 255) / 256, 256, 0, stream>>>(dst, degc, E);
    k_scanA<<<nA, 256, 0, stream>>>(degc, exscan, bsum, N);
    k_scanB<<<1, 512, 0, stream>>>(bsum, nA);
    k_scanC<<<nA, 256, 0, stream>>>(degc, exscan, bsum, rowptr, dinv, N);
    k_fillpad<<<(E + N + 255) / 256, 256, 0, stream>>>(src, dst, degc, rowptr, cursor, colp, E, N);
    k_wprep<<<80, 256, 0, stream>>>(W1, W2, Wt, W2t);
    k_mm1<<<(N + 63) / 64, 256, 0, stream>>>(x, Wt, dinv, hs1, N);
    k_aggmm2<<<(N + 64) / 64, 256, 0, stream>>>(rowptr, colp, dinv, hs1, b1, W2t, hs2, N);
    k_agg2<<<2048, 256, 0, stream>>>(rowptr, colp, dinv, hs2, out, colsum, N);
    k_final<<<(N + 127) / 128, 128, 0, stream>>>(out, colsum, N);
}

// Round 11
// 396.872 us; speedup vs baseline: 1.0483x; 1.0483x over previous
//
#include <hip/hip_runtime.h>
#include <hip/hip_fp16.h>
#include <math.h>

#define F_IN  256
#define F_HID 64
#define F_OUT 40
#define HS2_LD 64   // fp16 row stride: 64*2B = one 128B line

typedef _Float16 h8 __attribute__((ext_vector_type(8)));
typedef _Float16 h4 __attribute__((ext_vector_type(4)));
typedef float f4 __attribute__((ext_vector_type(4)));

// ---------------------------------------------------------------- deg histogram + weight prep (merged)
__global__ void k_degw(const int* __restrict__ dst, unsigned* __restrict__ degc, int E,
                       const float* __restrict__ W1, const float* __restrict__ W2,
                       __half* __restrict__ Wt, __half* __restrict__ W2t) {
    int i = blockIdx.x * 256 + threadIdx.x;
    if (i < E) {
        atomicAdd(&degc[dst[i]], 1u);
        return;
    }
    int j = i - E;
    if (j < 16384) {
        int k = j >> 6, n = j & 63;
        Wt[n * 256 + k] = __float2half(W1[j]);
    } else if (j < 20480) {
        int jj = j - 16384;
        int n = jj >> 6, k = jj & 63;
        W2t[n * 64 + k] = __float2half((n < F_OUT) ? W2[k * F_OUT + n] : 0.f);
    }
}

// ---------------------------------------------------------------- single-kernel scan (decoupled lookback)
// pdeg = (deg+8)&~7. Publishes agg (flag 1) then prefix (flag 3) in aggf[b];
// value in low 30 bits (total padded size < 2^30). Ticket-ordered blocks; 391 blocks
// all co-resident (2048 slots) -> no deadlock. Also zeroes cursor and colsum.
__global__ __launch_bounds__(256) void k_scan(const unsigned* __restrict__ degc,
                                              unsigned* __restrict__ aggf,
                                              unsigned* __restrict__ ticket,
                                              unsigned* __restrict__ rowptr,
                                              float* __restrict__ dinv,
                                              unsigned* __restrict__ cursor,
                                              float* __restrict__ colsum, int N) {
    __shared__ unsigned s[256];
    __shared__ unsigned sTick, sPfx, sTot;
    int tid = threadIdx.x;
    if (tid == 0) sTick = atomicAdd(ticket, 1u);
    if (blockIdx.x == 0 && tid < 64) colsum[tid] = 0.f;
    __syncthreads();
    unsigned b = sTick;
    int i = (int)b * 256 + tid;
    unsigned d = (i < N) ? degc[i] : 0u;
    unsigned v = (i < N) ? ((d + 8u) & ~7u) : 0u;
    s[tid] = v;
    __syncthreads();
    for (int off = 1; off < 256; off <<= 1) {
        unsigned t = (tid >= off) ? s[tid - off] : 0u;
        __syncthreads();
        s[tid] += t;
        __syncthreads();
    }
    unsigned incl = s[tid];
    if (tid == 255) {
        sTot = s[255];
        atomicExch(&aggf[b], s[255] | 0x40000000u);  // publish aggregate
    }
    __syncthreads();
    if (tid == 0) {
        unsigned run = 0;
        int pr = (int)b - 1;
        while (pr >= 0) {
            unsigned t;
            do { t = atomicAdd(&aggf[pr], 0u); } while ((t >> 30) == 0u);
            run += t & 0x3FFFFFFFu;
            if ((t >> 30) == 3u) break;  // inclusive prefix found
            --pr;
        }
        sPfx = run;
        atomicExch(&aggf[b], (run + sTot) | 0xC0000000u);  // publish prefix
    }
    __syncthreads();
    unsigned pfx = sPfx;
    if (i < N) {
        rowptr[i] = pfx + incl - v;
        dinv[i] = rsqrtf((float)d + 1.0f);  // +1 self loop
        cursor[i] = 0u;
        if (i == N - 1) rowptr[N] = pfx + incl;
    }
    if (i == 0) dinv[N] = 1.0f;  // sentinel
}

// ---------------------------------------------------------------- fill + pad (pad parallel: 8 thr/node)
__global__ void k_fillpad(const int* __restrict__ src, const int* __restrict__ dst,
                          const unsigned* __restrict__ degc,
                          const unsigned* __restrict__ rowptr, unsigned* __restrict__ cursor,
                          unsigned* __restrict__ colp, int E, int N) {
    int t = blockIdx.x * blockDim.x + threadIdx.x;
    if (t < E) {
        int d = dst[t];
        unsigned p = atomicAdd(&cursor[d], 1u);
        colp[rowptr[d] + p] = (unsigned)src[t];
    } else {
        int r = t - E;
        int i = r >> 3, j = r & 7;
        if (i < N) {
            unsigned d = degc[i];
            unsigned pd = (d + 8u) & ~7u;
            unsigned slot = d + (unsigned)j;
            if (slot < pd) colp[rowptr[i] + slot] = (j == 0) ? (unsigned)i : (unsigned)N;
        }
    }
}

// ---------------------------------------------------------------- hs1 = (x @ W1) * dinv, fp16, MFMA
#define XS 136
__global__ __launch_bounds__(256) void k_mm1(const float* __restrict__ x,
                                             const __half* __restrict__ Wth,
                                             const float* __restrict__ dinv,
                                             __half* __restrict__ hs1o, int N) {
    __shared__ _Float16 sX[64 * XS];  // 17408 B
    const _Float16* Wt = (const _Float16*)Wth;
    _Float16* hs1 = (_Float16*)hs1o;
    int tid = threadIdx.x;
    int lane = tid & 63;
    int wv = tid >> 6;
    int m15 = lane & 15;
    int q = lane >> 4;
    int nbase = blockIdx.x * 64;

    h8 bf[8];
    #pragma unroll
    for (int kt = 0; kt < 8; ++kt)
        bf[kt] = *(const h8*)(Wt + (wv * 16 + m15) * 256 + kt * 32 + q * 8);

    f4 acc[4];
    #pragma unroll
    for (int mt = 0; mt < 4; ++mt) acc[mt] = (f4){0.f, 0.f, 0.f, 0.f};

    #pragma unroll
    for (int c = 0; c < 2; ++c) {
        #pragma unroll
        for (int p = 0; p < 8; ++p) {
            int idx = p * 256 + tid;
            int row = idx >> 5;
            int c4  = idx & 31;
            int node = nbase + row;
            float4 v = (node < N) ? *(const float4*)(x + (size_t)node * F_IN + c * 128 + c4 * 4)
                                  : make_float4(0.f, 0.f, 0.f, 0.f);
            h4 hv = { (_Float16)v.x, (_Float16)v.y, (_Float16)v.z, (_Float16)v.w };
            *(h4*)&sX[row * XS + c4 * 4] = hv;
        }
        __syncthreads();
        #pragma unroll
        for (int kt2 = 0; kt2 < 4; ++kt2) {
            #pragma unroll
            for (int mt = 0; mt < 4; ++mt) {
                h8 a = *(const h8*)&sX[(mt * 16 + m15) * XS + kt2 * 32 + q * 8];
                acc[mt] = __builtin_amdgcn_mfma_f32_16x16x32_f16(a, bf[c * 4 + kt2], acc[mt], 0, 0, 0);
            }
        }
        __syncthreads();
    }

    #pragma unroll
    for (int mt = 0; mt < 4; ++mt) {
        #pragma unroll
        for (int r = 0; r < 4; ++r) {
            int node = nbase + mt * 16 + q * 4 + r;
            if (node <= N) {
                float din = (node < N) ? dinv[node] : 1.0f;
                hs1[(size_t)node * F_HID + wv * 16 + m15] = (_Float16)(acc[mt][r] * din);
            }
        }
    }
}

// ---------------------------------------------------------------- gather layer 1 (fp16, vectorized)
__global__ __launch_bounds__(256) void k_agg1(const unsigned* __restrict__ rowptr,
                                              const unsigned* __restrict__ colp,
                                              const float* __restrict__ dinv,
                                              const __half* __restrict__ hs1o,
                                              const float* __restrict__ bias1,
                                              __half* __restrict__ agg1o, int N) {
    const _Float16* hp = (const _Float16*)hs1o;
    _Float16* agg1h = (_Float16*)agg1o;
    int lane = threadIdx.x & 63;
    int w = blockIdx.x * 4 + (threadIdx.x >> 6);
    int na = 2 * w, nb = 2 * w + 1;
    if (na >= N) return;
    int g = lane >> 3, c = lane & 7;

    float accA[8], accB[8];
    #pragma unroll
    for (int j = 0; j < 8; ++j) { accA[j] = 0.f; accB[j] = 0.f; }

    unsigned aE = rowptr[na], aEnd = rowptr[na + 1];
    bool hasB = (nb < N);
    unsigned bE = 0, bEnd = 0;
    if (hasB) { bE = rowptr[nb]; bEnd = rowptr[nb + 1]; }

    while (aE < aEnd && bE < bEnd) {
        unsigned sA = colp[aE + g];
        unsigned sB = colp[bE + g];
        h8 va = *(const h8*)(hp + (size_t)sA * F_HID + c * 8);
        h8 vb = *(const h8*)(hp + (size_t)sB * F_HID + c * 8);
        #pragma unroll
        for (int j = 0; j < 8; ++j) { accA[j] += (float)va[j]; accB[j] += (float)vb[j]; }
        aE += 8; bE += 8;
    }
    while (aE < aEnd) {
        unsigned sA = colp[aE + g];
        h8 va = *(const h8*)(hp + (size_t)sA * F_HID + c * 8);
        #pragma unroll
        for (int j = 0; j < 8; ++j) accA[j] += (float)va[j];
        aE += 8;
    }
    while (bE < bEnd) {
        unsigned sB = colp[bE + g];
        h8 vb = *(const h8*)(hp + (size_t)sB * F_HID + c * 8);
        #pragma unroll
        for (int j = 0; j < 8; ++j) accB[j] += (float)vb[j];
        bE += 8;
    }

    #pragma unroll
    for (int off = 8; off <= 32; off <<= 1) {
        #pragma unroll
        for (int j = 0; j < 8; ++j) {
            accA[j] += __shfl_xor(accA[j], off, 64);
            accB[j] += __shfl_xor(accB[j], off, 64);
        }
    }

    if (g == 0) {
        float bv[8];
        *(float4*)&bv[0] = *(const float4*)(bias1 + c * 8);
        *(float4*)&bv[4] = *(const float4*)(bias1 + c * 8 + 4);
        float dinA = dinv[na];
        h8 ho;
        #pragma unroll
        for (int j = 0; j < 8; ++j) ho[j] = (_Float16)fmaxf(accA[j] * dinA + bv[j], 0.f);
        *(h8*)(agg1h + (size_t)na * F_HID + c * 8) = ho;
        if (hasB) {
            float dinB = dinv[nb];
            #pragma unroll
            for (int j = 0; j < 8; ++j) ho[j] = (_Float16)fmaxf(accB[j] * dinB + bv[j], 0.f);
            *(h8*)(agg1h + (size_t)nb * F_HID + c * 8) = ho;
        }
    }
}

// ---------------------------------------------------------------- hs2 = (agg1 @ W2) * dinv, fp16, MFMA
#define AS 72   // 144 B LDS row stride: 16B-aligned, bank-stride 4 (2-way, free)
__global__ __launch_bounds__(256) void k_mm2(const __half* __restrict__ agg1o,
                                             const __half* __restrict__ W2th,
                                             const float* __restrict__ dinv,
                                             __half* __restrict__ hs2o, int N) {
    __shared__ _Float16 sA[64 * AS];  // 9216 B
    const _Float16* agg1h = (const _Float16*)agg1o;
    const _Float16* W2t = (const _Float16*)W2th;
    _Float16* hs2 = (_Float16*)hs2o;
    int tid = threadIdx.x;
    int lane = tid & 63;
    int wv = tid >> 6;
    int m15 = lane & 15;
    int q = lane >> 4;
    int nbase = blockIdx.x * 64;

    h8 bf[2];
    #pragma unroll
    for (int kt = 0; kt < 2; ++kt)
        bf[kt] = *(const h8*)(W2t + (wv * 16 + m15) * 64 + kt * 32 + q * 8);

    #pragma unroll
    for (int p = 0; p < 2; ++p) {
        int idx = p * 256 + tid;
        int row = idx >> 3;
        int c8  = idx & 7;
        int node = nbase + row;
        h8 v;
        if (node < N) v = *(const h8*)(agg1h + (size_t)node * F_HID + c8 * 8);
        else          v = (h8){0, 0, 0, 0, 0, 0, 0, 0};
        *(h8*)&sA[row * AS + c8 * 8] = v;
    }
    __syncthreads();

    f4 acc[4];
    #pragma unroll
    for (int mt = 0; mt < 4; ++mt) acc[mt] = (f4){0.f, 0.f, 0.f, 0.f};
    #pragma unroll
    for (int kt = 0; kt < 2; ++kt) {
        #pragma unroll
        for (int mt = 0; mt < 4; ++mt) {
            h8 a = *(const h8*)&sA[(mt * 16 + m15) * AS + kt * 32 + q * 8];
            acc[mt] = __builtin_amdgcn_mfma_f32_16x16x32_f16(a, bf[kt], acc[mt], 0, 0, 0);
        }
    }

    #pragma unroll
    for (int mt = 0; mt < 4; ++mt) {
        #pragma unroll
        for (int r = 0; r < 4; ++r) {
            int node = nbase + mt * 16 + q * 4 + r;
            if (node <= N) {
                float din = (node < N) ? dinv[node] : 1.0f;
                hs2[(size_t)node * HS2_LD + wv * 16 + m15] = (_Float16)(acc[mt][r] * din);
            }
        }
    }
}

// ---------------------------------------------------------------- gather layer 2 (fp16, vectorized)
__global__ __launch_bounds__(256) void k_agg2(const unsigned* __restrict__ rowptr,
                                              const unsigned* __restrict__ colp,
                                              const float* __restrict__ dinv,
                                              const __half* __restrict__ hs2o,
                                              float* __restrict__ out,
                                              float* __restrict__ colsum, int N) {
    __shared__ float part[4][8][8];
    const _Float16* hp = (const _Float16*)hs2o;
    int lane = threadIdx.x & 63;
    int wv = threadIdx.x >> 6;
    int g = lane >> 3, c = lane & 7;
    int nwaves = gridDim.x * 4;
    float csum[8];
    #pragma unroll
    for (int j = 0; j < 8; ++j) csum[j] = 0.f;

    for (int w = blockIdx.x * 4 + wv; 2 * w < N; w += nwaves) {
        int na = 2 * w, nb = 2 * w + 1;
        float accA[8], accB[8];
        #pragma unroll
        for (int j = 0; j < 8; ++j) { accA[j] = 0.f; accB[j] = 0.f; }

        unsigned aE = rowptr[na], aEnd = rowptr[na + 1];
        bool hasB = (nb < N);
        unsigned bE = 0, bEnd = 0;
        if (hasB) { bE = rowptr[nb]; bEnd = rowptr[nb + 1]; }

        while (aE < aEnd && bE < bEnd) {
            unsigned sA = colp[aE + g];
            unsigned sB = colp[bE + g];
            h8 va = *(const h8*)(hp + (size_t)sA * HS2_LD + c * 8);
            h8 vb = *(const h8*)(hp + (size_t)sB * HS2_LD + c * 8);
            #pragma unroll
            for (int j = 0; j < 8; ++j) { accA[j] += (float)va[j]; accB[j] += (float)vb[j]; }
            aE += 8; bE += 8;
        }
        while (aE < aEnd) {
            unsigned sA = colp[aE + g];
            h8 va = *(const h8*)(hp + (size_t)sA * HS2_LD + c * 8);
            #pragma unroll
            for (int j = 0; j < 8; ++j) accA[j] += (float)va[j];
            aE += 8;
        }
        while (bE < bEnd) {
            unsigned sB = colp[bE + g];
            h8 vb = *(const h8*)(hp + (size_t)sB * HS2_LD + c * 8);
            #pragma unroll
            for (int j = 0; j < 8; ++j) accB[j] += (float)vb[j];
            bE += 8;
        }

        #pragma unroll
        for (int off = 8; off <= 32; off <<= 1) {
            #pragma unroll
            for (int j = 0; j < 8; ++j) {
                accA[j] += __shfl_xor(accA[j], off, 64);
                accB[j] += __shfl_xor(accB[j], off, 64);
            }
        }

        if (g == 0) {
            float dinA = dinv[na];
            #pragma unroll
            for (int j = 0; j < 8; ++j) { accA[j] *= dinA; csum[j] += accA[j]; }
            if (c < 5) {
                *(float4*)(out + (size_t)na * F_OUT + c * 8) =
                    make_float4(accA[0], accA[1], accA[2], accA[3]);
                *(float4*)(out + (size_t)na * F_OUT + c * 8 + 4) =
                    make_float4(accA[4], accA[5], accA[6], accA[7]);
            }
            if (hasB) {
                float dinB = dinv[nb];
                #pragma unroll
                for (int j = 0; j < 8; ++j) { accB[j] *= dinB; csum[j] += accB[j]; }
                if (c < 5) {
                    *(float4*)(out + (size_t)nb * F_OUT + c * 8) =
                        make_float4(accB[0], accB[1], accB[2], accB[3]);
                    *(float4*)(out + (size_t)nb * F_OUT + c * 8 + 4) =
                        make_float4(accB[4], accB[5], accB[6], accB[7]);
                }
            }
        }
    }

    if (g == 0) {
        #pragma unroll
        for (int j = 0; j < 8; ++j) part[wv][c][j] = csum[j];
    }
    __syncthreads();
    int tid = threadIdx.x;
    if (tid < F_OUT) {
        int cc = tid >> 3, jj = tid & 7;
        float s = part[0][cc][jj] + part[1][cc][jj] + part[2][cc][jj] + part[3][cc][jj];
        atomicAdd(&colsum[tid], s);
    }
}

// ---------------------------------------------------------------- PairNorm-SI + log_softmax
__global__ __launch_bounds__(128) void k_final(float* __restrict__ out,
                                               const float* __restrict__ colsum, int N) {
    __shared__ float sMean[F_OUT];
    if (threadIdx.x < F_OUT) sMean[threadIdx.x] = colsum[threadIdx.x] * (1.0f / (float)N);
    __syncthreads();
    int n = blockIdx.x * blockDim.x + threadIdx.x;
    if (n >= N) return;
    float* row = out + (size_t)n * F_OUT;
    float v[F_OUT];
    float ss = 0.f;
    #pragma unroll
    for (int f = 0; f < F_OUT; ++f) {
        float t = row[f] - sMean[f];
        v[f] = t;
        ss += t * t;
    }
    float scale = 1.0f / sqrtf(ss + 1e-6f);
    float m = -1e30f;
    #pragma unroll
    for (int f = 0; f < F_OUT; ++f) {
        float y = v[f] * scale;
        v[f] = y;
        m = fmaxf(m, y);
    }
    float sum = 0.f;
    #pragma unroll
    for (int f = 0; f < F_OUT; ++f) sum += expf(v[f] - m);
    float lse = logf(sum);
    #pragma unroll
    for (int f = 0; f < F_OUT; ++f) row[f] = v[f] - m - lse;
}

extern "C" void kernel_launch(void* const* d_in, const int* in_sizes, int n_in,
                              void* d_out, int out_size, void* d_ws, size_t ws_size,
                              hipStream_t stream) {
    const float* x  = (const float*)d_in[0];
    const int*   ei = (const int*)d_in[1];   // int32 per harness (verified R1)
    const float* W1 = (const float*)d_in[2];
    const float* b1 = (const float*)d_in[3];
    const float* W2 = (const float*)d_in[4];
    // b2 unused: cancels under PairNorm mean subtraction.
    float* out = (float*)d_out;

    int N = in_sizes[0] / F_IN;
    int E = in_sizes[1] / 2;
    const int* src = ei;
    const int* dst = ei + E;

    // byte layout with 128B alignment per region.
    // memset zone: degc + aggf + ticket (must precede everything else).
    char* p = (char*)d_ws;
    auto alloc = [&](size_t bytes) { char* r = p; p += (bytes + 127) & ~(size_t)127; return r; };
    unsigned* degc   = (unsigned*)alloc((size_t)N * 4);
    unsigned* aggf   = (unsigned*)alloc(512 * 4);
    unsigned* ticket = (unsigned*)alloc(4);
    char* zend = p;  // end of memset zone
    unsigned* cursor = (unsigned*)alloc((size_t)N * 4);
    float*    colsum = (float*)   alloc(64 * 4);
    unsigned* rowptr = (unsigned*)alloc((size_t)(N + 1) * 4);
    unsigned* colp   = (unsigned*)alloc((size_t)(E + 8 * N + 8) * 4);
    float*    dinv   = (float*)   alloc((size_t)(N + 1) * 4);
    __half*   agg1h  = (__half*)  alloc((size_t)64 * (N + 1) * 2);
    __half*   hs1    = (__half*)  alloc((size_t)64 * (N + 1) * 2);
    __half*   hs2    = (__half*)  alloc((size_t)64 * (N + 1) * 2);
    __half*   Wt     = (__half*)  alloc((size_t)16384 * 2);
    __half*   W2t    = (__half*)  alloc((size_t)4096 * 2);

    hipMemsetAsync(d_ws, 0, (size_t)(zend - (char*)d_ws), stream);

    int nA = (N + 255) / 256;  // 391 for N=100000 (<512 aggf slots)
    k_degw<<<(E + 20480 + 255) / 256, 256, 0, stream>>>(dst, degc, E, W1, W2, Wt, W2t);
    k_scan<<<nA, 256, 0, stream>>>(degc, aggf, ticket, rowptr, dinv, cursor, colsum, N);
    k_fillpad<<<(E + 8 * N + 255) / 256, 256, 0, stream>>>(src, dst, degc, rowptr, cursor, colp, E, N);
    k_mm1<<<(N + 63) / 64, 256, 0, stream>>>(x, Wt, dinv, hs1, N);
    int waves1 = (N + 1) / 2;
    k_agg1<<<(waves1 + 3) / 4, 256, 0, stream>>>(rowptr, colp, dinv, hs1, b1, agg1h, N);
    k_mm2<<<(N + 64) / 64, 256, 0, stream>>>(agg1h, W2t, dinv, hs2, N);
    k_agg2<<<2048, 256, 0, stream>>>(rowptr, colp, dinv, hs2, out, colsum, N);
    k_final<<<(N + 127) / 128, 128, 0, stream>>>(out, colsum, N);
}